// Round 1
// baseline (351.451 us; speedup 1.0000x reference)
//
#include <hip/hip_runtime.h>
#include <cstdint>
#include <cstddef>

// ---------------- workspace layout ----------------
// xp  : [32][58][58][256] bf16  (NHWC, spatial halo of zeros)  = 55,115,776 B
// Wb  : [256][2304] bf16 (sign(w) as +-1; k = tap*256 + c)     =  1,179,648 B
// alpha: [256] f32                                              =      1,024 B
#define XP_BYTES 55115776ull
#define WB_OFF   55115776ull
#define AL_OFF   (WB_OFF + 1179648ull)

typedef __bf16 bf16x8 __attribute__((ext_vector_type(8)));
typedef float  f32x4  __attribute__((ext_vector_type(4)));

static __device__ __forceinline__ unsigned short f2bf(float f) {
  union { float f; unsigned int u; } v; v.f = f;
  unsigned int u = v.u;
  u += 0x7FFFu + ((u >> 16) & 1u);   // RNE
  return (unsigned short)(u >> 16);
}

static __device__ __forceinline__ void async16(void* lds, const void* g) {
  __builtin_amdgcn_global_load_lds(
      (const __attribute__((address_space(1))) unsigned int*)g,
      (__attribute__((address_space(3))) unsigned int*)lds, 16, 0, 0);
}

// ---------------- weight prep: alpha[o] + sign(w) in bf16, k = tap*256+c ----
__global__ void prep_w(const float* __restrict__ w, unsigned short* __restrict__ wb,
                       float* __restrict__ alpha) {
  const int o = blockIdx.x, c = threadIdx.x;
  const float* wr = w + (size_t)(o * 256 + c) * 9;
  float s = 0.f;
#pragma unroll
  for (int tap = 0; tap < 9; ++tap) {
    float v = wr[tap];
    s += fabsf(v);
    unsigned short sg = (v > 0.f) ? 0x3F80u : ((v < 0.f) ? 0xBF80u : 0u);
    wb[(size_t)o * 2304 + tap * 256 + c] = sg;
  }
  __shared__ float red[256];
  red[c] = s;
  __syncthreads();
  for (int d = 128; d > 0; d >>= 1) {
    if (c < d) red[c] += red[c + d];
    __syncthreads();
  }
  if (c == 0) alpha[o] = red[0] * (1.f / 2304.f);
}

// ---------------- x prep: NCHW f32 -> NHWC bf16 with halo ----------------
// grid = 32*58 blocks (one per (n, padded-row)), 256 threads.
__global__ void prep_x(const float* __restrict__ x, unsigned short* __restrict__ xp) {
  const int bx = blockIdx.x;
  const int n = bx / 58, hp = bx % 58;
  const int t = threadIdx.x;
  unsigned short* row = xp + (size_t)(n * 58 + hp) * 58 * 256;

  if (hp == 0 || hp == 57) {            // halo rows: all zero (58*256 ushort)
    uint32_t* r32 = (uint32_t*)row;
    for (int i = t; i < 7424; i += 256) r32[i] = 0;
    return;
  }
  const int h = hp - 1;
  const int c2 = (t & 127) * 2;         // channel pair
  const int rep = t >> 7;               // 0: w 0..27, 1: w 28..55
  const int w0 = rep * 28;
  const float* x0 = x + ((size_t)(n * 256 + c2) * 56 + h) * 56;
  const float* x1 = x0 + (size_t)56 * 56;

  if (rep == 0) {                        // halo columns w'=0 and w'=57
    ((uint32_t*)row)[c2 >> 1] = 0;
    ((uint32_t*)(row + 57 * 256))[c2 >> 1] = 0;
  }
#pragma unroll
  for (int i = 0; i < 7; ++i) {
    float4 a = *(const float4*)(x0 + w0 + i * 4);
    float4 b = *(const float4*)(x1 + w0 + i * 4);
    unsigned short va[4] = {f2bf(a.x), f2bf(a.y), f2bf(a.z), f2bf(a.w)};
    unsigned short vb[4] = {f2bf(b.x), f2bf(b.y), f2bf(b.z), f2bf(b.w)};
    const int wbase = w0 + i * 4;
#pragma unroll
    for (int j = 0; j < 4; ++j) {
      uint32_t pack = (uint32_t)va[j] | ((uint32_t)vb[j] << 16);
      ((uint32_t*)(row + (size_t)(wbase + j + 1) * 256))[c2 >> 1] = pack;
    }
  }
}

// ---------------- implicit-GEMM conv: C[o][pix] = Wb * Xp ----------------
// M=256 (2 tiles of 128), N=100352 (784 tiles of 128), K=2304 (72 iters of 32)
__global__ __launch_bounds__(256, 3)
void conv_mfma(const unsigned short* __restrict__ xp,
               const unsigned short* __restrict__ wb,
               const float* __restrict__ alpha,
               float* __restrict__ out) {
  __shared__ __align__(16) char lds[16384];
  char* ldsA = lds;            // 128 rows (o)   x 32 k bf16, 64 B rows
  char* ldsB = lds + 8192;     // 128 rows (pix) x 32 k bf16, 64 B rows

  const int tid = threadIdx.x;
  const int wave = tid >> 6, lane = tid & 63;
  const int wm = wave >> 1, wn = wave & 1;
  const int o0 = (blockIdx.x & 1) * 128;
  const int pix0 = (blockIdx.x >> 1) * 128;

  const int chunk = lane & 3;        // 16B chunk within 64B row
  const int rsub = lane >> 2;        // row within 16-row group

  const char* wbB = (const char*)wb;
  const char* xpB = (const char*)xp;
  const char* gA[2];
  const char* gB[2];
#pragma unroll
  for (int j = 0; j < 2; ++j) {
    const int row = (wave * 2 + j) * 16 + rsub;           // 0..127
    gA[j] = wbB + ((size_t)(o0 + row) * 2304 + chunk * 8) * 2;
    const int pix = pix0 + row;
    const int n = pix / 3136, rem = pix % 3136;
    const int h = rem / 56, w = rem % 56;
    gB[j] = xpB + (size_t)((n * 58 + h) * 58 + w) * 512 + chunk * 16;
  }

  f32x4 acc[4][4];
#pragma unroll
  for (int i = 0; i < 4; ++i)
#pragma unroll
    for (int j = 0; j < 4; ++j) acc[i][j] = (f32x4){0.f, 0.f, 0.f, 0.f};

  const int ar = lane & 15, aq = lane >> 4;

  for (int tap = 0; tap < 9; ++tap) {
    const int kh = tap / 3, kw = tap % 3;
    const int tapoff = (kh * 58 + kw) * 512;
#pragma unroll
    for (int cc = 0; cc < 8; ++cc) {
      const int kA = (tap * 256 + cc * 32) * 2;   // byte offset into Wb row
      const int kB = tapoff + cc * 64;            // byte offset into xp
      __syncthreads();                            // prev-iter frag reads done
      async16(ldsA + (wave * 2 + 0) * 1024, gA[0] + kA);
      async16(ldsA + (wave * 2 + 1) * 1024, gA[1] + kA);
      async16(ldsB + (wave * 2 + 0) * 1024, gB[0] + kB);
      async16(ldsB + (wave * 2 + 1) * 1024, gB[1] + kB);
      __syncthreads();                            // vmcnt(0) drained here

      bf16x8 af[4], bfr[4];
#pragma unroll
      for (int mi = 0; mi < 4; ++mi)
        af[mi] = *(const bf16x8*)(ldsA + ((wm * 64 + mi * 16 + ar) * 64 + aq * 16));
#pragma unroll
      for (int ni = 0; ni < 4; ++ni)
        bfr[ni] = *(const bf16x8*)(ldsB + ((wn * 64 + ni * 16 + ar) * 64 + aq * 16));
#pragma unroll
      for (int mi = 0; mi < 4; ++mi)
#pragma unroll
        for (int ni = 0; ni < 4; ++ni)
          acc[mi][ni] = __builtin_amdgcn_mfma_f32_16x16x32_bf16(af[mi], bfr[ni], acc[mi][ni], 0, 0, 0);
    }
  }

  // epilogue: D[row=o][col=pix], col=lane&15, row=(lane>>4)*4+r ; scale by alpha[o]
  int nc[4], rc[4];
#pragma unroll
  for (int ni = 0; ni < 4; ++ni) {
    const int pix = pix0 + wn * 64 + ni * 16 + ar;
    nc[ni] = pix / 3136; rc[ni] = pix % 3136;
  }
#pragma unroll
  for (int mi = 0; mi < 4; ++mi) {
    const int orow = o0 + wm * 64 + mi * 16 + aq * 4;
    float al[4];
#pragma unroll
    for (int r = 0; r < 4; ++r) al[r] = alpha[orow + r];
#pragma unroll
    for (int ni = 0; ni < 4; ++ni) {
      const size_t base = (size_t)nc[ni] * 802816 + (size_t)orow * 3136 + (size_t)rc[ni];
#pragma unroll
      for (int r = 0; r < 4; ++r)
        out[base + (size_t)r * 3136] = acc[mi][ni][r] * al[r];
    }
  }
}

extern "C" void kernel_launch(void* const* d_in, const int* in_sizes, int n_in,
                              void* d_out, int out_size, void* d_ws, size_t ws_size,
                              hipStream_t stream) {
  const float* x = (const float*)d_in[0];
  const float* w = (const float*)d_in[1];
  char* ws = (char*)d_ws;
  unsigned short* xp  = (unsigned short*)ws;
  unsigned short* wbp = (unsigned short*)(ws + WB_OFF);
  float* alpha = (float*)(ws + AL_OFF);
  float* out = (float*)d_out;

  prep_w<<<256, 256, 0, stream>>>(w, wbp, alpha);
  prep_x<<<32 * 58, 256, 0, stream>>>(x, xp);
  conv_mfma<<<1568, 256, 0, stream>>>(xp, wbp, alpha, out);
}